// Round 2
// baseline (175.130 us; speedup 1.0000x reference)
//
#include <hip/hip_runtime.h>

#define BB 32
#define SS 50
#define DDk 4
#define NI 5000

// ---------------------------------------------------------------------------
// k_prep: blocks 0..63 copy Wd into Wcat rows [0,512); blocks 64..127 compute
// Wcomb: Wcat[512 + d*128 + o][e] = sum_h Ws[o*256+128+h] * Wd[(d*128+h)*128+e]
// ---------------------------------------------------------------------------
__global__ __launch_bounds__(256) void k_prep(const float* __restrict__ Wd,
                                              const float* __restrict__ Ws,
                                              float* __restrict__ Wcat) {
    int t = threadIdx.x;
    int blk = blockIdx.x;
    if (blk < 64) {
        int x = blk * 256 + t;               // 16384 float4s total
        ((float4*)Wcat)[x] = ((const float4*)Wd)[x];
        return;
    }
    __shared__ float wk[8][128];
    int cb = blk - 64;                        // 0..63
    int d = cb >> 4, ot = cb & 15;            // 8 o's per block
    for (int x = t; x < 8 * 128; x += 256) {
        int ol = x >> 7, h = x & 127;
        wk[ol][h] = Ws[(ot * 8 + ol) * 256 + 128 + h];
    }
    __syncthreads();
    int e = t & 127, og = t >> 7;             // og in {0,1}
    float acc[4] = {0.f, 0.f, 0.f, 0.f};
    for (int h = 0; h < 128; ++h) {
        float rd = Wd[(d * 128 + h) * 128 + e];
#pragma unroll
        for (int k = 0; k < 4; ++k) acc[k] += rd * wk[og * 4 + k][h];
    }
#pragma unroll
    for (int k = 0; k < 4; ++k) {
        int o = ot * 8 + og * 4 + k;
        Wcat[(size_t)(512 + d * 128 + o) * 128 + e] = acc[k];
    }
}

// ---------------------------------------------------------------------------
// k_gemm: out[r][c] = sum_e emb_table[idx[r]][e] * W[c][e],  K = 128.
// Block = 64 rows x 128 cols, two K-slices of 64. 8x4 outer product/thread.
// LDS: se[64][64], sw[128][64], XOR-chunk swizzle -> conflict-free b128 reads.
// Also writes the gathered embedding rows to emb_out (blocks with c0==0).
// ---------------------------------------------------------------------------
__global__ __launch_bounds__(256) void k_gemm(const int* __restrict__ idx,
                                              const float* __restrict__ et,
                                              const float* __restrict__ W,
                                              float* __restrict__ emb_out,
                                              float* __restrict__ out,
                                              int nrows, int C) {
    __shared__ float se[64 * 64];
    __shared__ float sw[128 * 64];
    int r0 = blockIdx.x * 64;
    int c0 = blockIdx.y * 128;
    int t = threadIdx.x;
    int ri = t & 7, ci = t >> 3;              // wave: ri 0..7 x ci 0..7
    float acc[8][4];
#pragma unroll
    for (int j = 0; j < 8; ++j)
#pragma unroll
        for (int k = 0; k < 4; ++k) acc[j][k] = 0.f;

    for (int ks = 0; ks < 2; ++ks) {
        int e0 = ks * 64;
        __syncthreads();                      // protect LDS before overwrite
        // stage se: 64 rows x 16 chunks (swizzled: cs = ch ^ (r>>3))
#pragma unroll
        for (int q = 0; q < 4; ++q) {
            int x = t + q * 256;              // 0..1023
            int r = x >> 4, ch = x & 15;
            int rg = r0 + r;
            float4 v = make_float4(0.f, 0.f, 0.f, 0.f);
            if (rg < nrows) {
                v = *(const float4*)(et + (size_t)idx[rg] * 128 + e0 + ch * 4);
                if (emb_out != nullptr && c0 == 0)
                    *(float4*)(emb_out + (size_t)rg * 128 + e0 + ch * 4) = v;
            }
            int cs = ch ^ ((r >> 3) & 7);
            *(float4*)(&se[r * 64 + cs * 4]) = v;
        }
        // stage sw: 128 cols x 16 chunks (swizzled: cs = ch ^ (c>>2))
#pragma unroll
        for (int q = 0; q < 8; ++q) {
            int x = t + q * 256;              // 0..2047
            int c = x >> 4, ch = x & 15;
            float4 v = *(const float4*)(W + (size_t)(c0 + c) * 128 + e0 + ch * 4);
            int cs = ch ^ ((c >> 2) & 7);
            *(float4*)(&sw[c * 64 + cs * 4]) = v;
        }
        __syncthreads();
#pragma unroll
        for (int ch = 0; ch < 16; ++ch) {
            int bs = (ch ^ (ci & 7)) << 2;
            float4 b0 = *(const float4*)(&sw[(ci * 4 + 0) * 64 + bs]);
            float4 b1 = *(const float4*)(&sw[(ci * 4 + 1) * 64 + bs]);
            float4 b2 = *(const float4*)(&sw[(ci * 4 + 2) * 64 + bs]);
            float4 b3 = *(const float4*)(&sw[(ci * 4 + 3) * 64 + bs]);
            int as = (ch ^ ri) << 2;
#pragma unroll
            for (int j = 0; j < 8; ++j) {
                float4 a = *(const float4*)(&se[(ri * 8 + j) * 64 + as]);
                acc[j][0] += a.x * b0.x + a.y * b0.y + a.z * b0.z + a.w * b0.w;
                acc[j][1] += a.x * b1.x + a.y * b1.y + a.z * b1.z + a.w * b1.w;
                acc[j][2] += a.x * b2.x + a.y * b2.y + a.z * b2.z + a.w * b2.w;
                acc[j][3] += a.x * b3.x + a.y * b3.y + a.z * b3.z + a.w * b3.w;
            }
        }
    }
#pragma unroll
    for (int j = 0; j < 8; ++j) {
        int rg = r0 + ri * 8 + j;
        if (rg < nrows) {
            float4 v = make_float4(acc[j][0], acc[j][1], acc[j][2], acc[j][3]);
            *(float4*)(out + (size_t)rg * C + c0 + ci * 4) = v;
        }
    }
}

// ---------------------------------------------------------------------------
// k_agg: agg[b*512+j] = log(sum_s exp(hid[(b*50+s)*1024 + j])), j in [0,512)
// ---------------------------------------------------------------------------
__global__ __launch_bounds__(256) void k_agg(const float* __restrict__ hid,
                                             float* __restrict__ agg) {
    int t = blockIdx.x * 256 + threadIdx.x;   // 0..16383
    int b = t >> 9, j = t & 511;
    const float* p = hid + (size_t)b * SS * 1024 + j;
    float s = 0.f;
    for (int si = 0; si < SS; ++si) s += expf(p[si * 1024]);
    agg[t] = logf(s);
}

// ---------------------------------------------------------------------------
// k_ap_loss: blocks 0..63: ap[bd*128+o] = b[o] + sum_h agg[bd*128+h]*Ws[o*256+h]
//            block 64: demand_sim_loss
// ---------------------------------------------------------------------------
__global__ __launch_bounds__(256) void k_ap_loss(const float* __restrict__ agg,
                                                 const float* __restrict__ Ws,
                                                 const float* __restrict__ bsc,
                                                 float* __restrict__ ap,
                                                 float* __restrict__ loss_out) {
    __shared__ float nrm[128];
    int t = threadIdx.x;
    if (blockIdx.x < 64) {
        int x = blockIdx.x * 256 + t;         // 0..16383
        int bd = x >> 7, o = x & 127;
        const float* a = agg + bd * 128;
        const float* w = Ws + o * 256;
        float acc = bsc[o];
        for (int ch = 0; ch < 32; ++ch) {
            float4 a4 = *(const float4*)(a + ch * 4);
            float4 w4 = *(const float4*)(w + ch * 4);
            acc += a4.x * w4.x + a4.y * w4.y + a4.z * w4.z + a4.w * w4.w;
        }
        ap[x] = acc;
        return;
    }
    if (t < 128) {
        const float* a = agg + t * 128;
        float s = 0.f;
        for (int h = 0; h < 128; ++h) s += a[h] * a[h];
        nrm[t] = fmaxf(sqrtf(s), 1e-8f);
    }
    __syncthreads();
    float lb = 0.f;
    if (t < 32) {
        const float* a = agg + t * 512;
        float i0 = 1.f / nrm[t * 4 + 0], i1 = 1.f / nrm[t * 4 + 1];
        float i2 = 1.f / nrm[t * 4 + 2], i3 = 1.f / nrm[t * 4 + 3];
        for (int h = 0; h < 128; ++h) {
            float u0 = a[h] * i0, u1 = a[128 + h] * i1;
            float u2 = a[256 + h] * i2, u3 = a[384 + h] * i3;
            float v = u0 + u1 + u2 + u3;
            lb += v * v - (u0 * u0 + u1 * u1 + u2 * u2 + u3 * u3);
        }
    }
    for (int off = 32; off; off >>= 1) lb += __shfl_down(lb, off);
    if (t == 0) loss_out[0] = lb / (float)(BB * DDk * (DDk - 1));
}

// ---------------------------------------------------------------------------
// k_score: demand_score[b][d][s] = sum_o w[o]*relu(ap[bd][o] + kp[bs][512+d*128+o])
// ---------------------------------------------------------------------------
__global__ __launch_bounds__(256) void k_score(const float* __restrict__ ap,
                                               const float* __restrict__ kp,
                                               const float* __restrict__ wsc,
                                               float* __restrict__ out) {
    int t = blockIdx.x * 256 + threadIdx.x;
    if (t >= BB * DDk * SS) return;
    int b = t / (DDk * SS);
    int rem = t - b * (DDk * SS);
    int d = rem / SS, s = rem - d * SS;
    const float* a = ap + (b * DDk + d) * 128;
    const float* k = kp + (size_t)(b * SS + s) * 1024 + 512 + d * 128;
    float acc = 0.f;
    for (int ch = 0; ch < 32; ++ch) {
        float4 a4 = *(const float4*)(a + ch * 4);
        float4 k4 = *(const float4*)(k + ch * 4);
        float4 w4 = *(const float4*)(wsc + ch * 4);
        acc += w4.x * fmaxf(a4.x + k4.x, 0.f) + w4.y * fmaxf(a4.y + k4.y, 0.f)
             + w4.z * fmaxf(a4.z + k4.z, 0.f) + w4.w * fmaxf(a4.w + k4.w, 0.f);
    }
    out[t] = acc;
}

// ---------------------------------------------------------------------------
// k_cand_score: out[b][d][i] = sum_o w[o]*relu(ap[bd][o] + cp[i][d*128+o])
// Block: fixed d, 64-i tile, all 32 b. XOR-swizzled LDS, float4 everywhere.
// ---------------------------------------------------------------------------
__global__ __launch_bounds__(256) void k_cand_score(const float* __restrict__ ap,
                                                    const float* __restrict__ cp,
                                                    const float* __restrict__ wsc,
                                                    float* __restrict__ out) {
    __shared__ float sap[32 * 128];
    __shared__ float scp[64 * 128];
    __shared__ float swv[128];
    const int ntiles = (NI + 63) / 64;        // 79
    int d = blockIdx.x / ntiles;
    int tile = blockIdx.x - d * ntiles;
    int i0 = tile * 64;
    int t = threadIdx.x;
    if (t < 128) swv[t] = wsc[t];
#pragma unroll
    for (int q = 0; q < 4; ++q) {             // sap: 32 rows x 32 chunks
        int x = t + q * 256;
        int b = x >> 5, ch = x & 31;
        float4 v = *(const float4*)(ap + (b * 4 + d) * 128 + ch * 4);
        int cs = ch ^ (b & 7);
        *(float4*)(&sap[b * 128 + cs * 4]) = v;
    }
#pragma unroll
    for (int q = 0; q < 8; ++q) {             // scp: 64 rows x 32 chunks
        int x = t + q * 256;
        int il = x >> 5, ch = x & 31;
        int i = i0 + il;
        float4 v = make_float4(0.f, 0.f, 0.f, 0.f);
        if (i < NI) v = *(const float4*)(cp + (size_t)i * 512 + d * 128 + ch * 4);
        int cs = ch ^ (il & 7);
        *(float4*)(&scp[il * 128 + cs * 4]) = v;
    }
    __syncthreads();
    int b = t >> 3, g = t & 7;
    float acc[8] = {0.f,0.f,0.f,0.f,0.f,0.f,0.f,0.f};
    const float* arow = sap + b * 128;
    for (int ch = 0; ch < 32; ++ch) {
        float4 a4 = *(const float4*)(arow + ((ch ^ (b & 7)) << 2));
        float4 w4 = *(const float4*)(swv + ch * 4);
#pragma unroll
        for (int kk = 0; kk < 8; ++kk) {
            int il = kk * 8 + g;
            float4 c4 = *(const float4*)(&scp[il * 128 + ((ch ^ g) << 2)]);
            acc[kk] += w4.x * fmaxf(a4.x + c4.x, 0.f) + w4.y * fmaxf(a4.y + c4.y, 0.f)
                     + w4.z * fmaxf(a4.z + c4.z, 0.f) + w4.w * fmaxf(a4.w + c4.w, 0.f);
        }
    }
#pragma unroll
    for (int kk = 0; kk < 8; ++kk) {
        int i = i0 + kk * 8 + g;
        if (i < NI) out[(size_t)b * (DDk * NI) + d * NI + i] = acc[kk];
    }
}

// ---------------------------------------------------------------------------
extern "C" void kernel_launch(void* const* d_in, const int* in_sizes, int n_in,
                              void* d_out, int out_size, void* d_ws, size_t ws_size,
                              hipStream_t stream) {
    const int*   inp  = (const int*)d_in[0];     // (B,S)
    const int*   cand = (const int*)d_in[1];     // (I,)
    const float* et   = (const float*)d_in[2];   // (N_CAT,E)
    const float* Wd   = (const float*)d_in[3];   // (D*H,E)
    const float* Ws   = (const float*)d_in[4];   // (H,2H)
    const float* bsc  = (const float*)d_in[5];   // (H,)
    const float* wsc  = (const float*)d_in[6];   // (H,)

    float* out = (float*)d_out;
    float* o_ds   = out;                  // (B,D,S)    6400
    float* o_dsc  = out + 6400;           // (B,D,I)    640000
    float* o_emb  = out + 646400;         // (B,S,E)    204800
    float* o_cemb = out + 851200;         // (I,E)      640000
    float* o_loss = out + 1491200;        // scalar

    float* ws    = (float*)d_ws;
    float* Wcat  = ws;                        // 1024*128      = 131072
    float* inhid = ws + 131072;               // 1600*1024     = 1638400 (hidden | kp)
    float* cp    = ws + 131072 + 1638400;     // 5000*512      = 2560000
    float* agg   = cp + 2560000;              // 16384
    float* ap    = agg + 16384;               // 16384

    // Wcat = [Wd (512x128) ; Wcomb (512x128)]
    hipLaunchKernelGGL(k_prep, dim3(128), dim3(256), 0, stream, Wd, Ws, Wcat);
    // inputs: hidden (cols 0..511) and key_proj (cols 512..1023) in one GEMM
    hipLaunchKernelGGL(k_gemm, dim3(25, 8), dim3(256), 0, stream,
                       inp, et, Wcat, o_emb, inhid, BB * SS, 1024);
    // candidates: cand_proj only (Wcomb part of Wcat)
    hipLaunchKernelGGL(k_gemm, dim3(79, 4), dim3(256), 0, stream,
                       cand, et, Wcat + 512 * 128, o_cemb, cp, NI, 512);
    hipLaunchKernelGGL(k_agg, dim3(64), dim3(256), 0, stream, inhid, agg);
    hipLaunchKernelGGL(k_ap_loss, dim3(65), dim3(256), 0, stream, agg, Ws, bsc, ap, o_loss);
    hipLaunchKernelGGL(k_score, dim3(25), dim3(256), 0, stream, ap, inhid, wsc, o_ds);
    hipLaunchKernelGGL(k_cand_score, dim3(4 * 79), dim3(256), 0, stream, ap, cp, wsc, o_dsc);
}

// Round 3
// 64.622 us; speedup vs baseline: 2.7101x; 2.7101x over previous
//
#include <hip/hip_runtime.h>

typedef __attribute__((ext_vector_type(8))) short short8;
typedef __attribute__((ext_vector_type(16))) float f32x16;

#define NROWS_IN 1600
#define NROWS_C  5000
#define NI 5000
#define BB 32
#define DDk 4
#define SS 50

__device__ __forceinline__ unsigned short f2bf(float f) {
    unsigned int u = __float_as_uint(f);
    u = (u + 0x7FFFu + ((u >> 16) & 1u)) >> 16;   // RNE
    return (unsigned short)u;
}

// ---------------------------------------------------------------------------
// k_prep: blk 0..15   : Wd (512x128 f32) -> Wcat[0..512) bf16
//         blk 16..79  : Wcomb[d*128+o][e] = sum_h Wk[o][h]*Wd[d*128+h][e] -> Wcat[512..1024) bf16
//         blk 80..904 : gather emb rows (input then cand) -> fp32 outputs + bf16 Abf
// ---------------------------------------------------------------------------
__global__ __launch_bounds__(256) void k_prep(const int* __restrict__ inp,
                                              const int* __restrict__ cand,
                                              const float* __restrict__ et,
                                              const float* __restrict__ Wd,
                                              const float* __restrict__ Ws,
                                              unsigned short* __restrict__ Wcat,
                                              unsigned short* __restrict__ Abf,
                                              float* __restrict__ o_emb,
                                              float* __restrict__ o_cemb) {
    int t = threadIdx.x;
    int blk = blockIdx.x;
    if (blk < 16) {
        const float4* src = (const float4*)Wd;
#pragma unroll
        for (int q = 0; q < 4; ++q) {
            int i = blk * 256 + t + q * 4096;   // 0..16383 float4s
            float4 v = src[i];
            ushort4 o;
            o.x = f2bf(v.x); o.y = f2bf(v.y); o.z = f2bf(v.z); o.w = f2bf(v.w);
            *(ushort4*)(Wcat + (size_t)i * 4) = o;
        }
        return;
    }
    if (blk < 80) {
        __shared__ float wk[8][128];
        int cb = blk - 16;                    // 0..63
        int d = cb >> 4, ot = cb & 15;
        for (int x = t; x < 8 * 128; x += 256) {
            int ol = x >> 7, h = x & 127;
            wk[ol][h] = Ws[(ot * 8 + ol) * 256 + 128 + h];
        }
        __syncthreads();
        int e = t & 127, og = t >> 7;
        float acc[4] = {0.f, 0.f, 0.f, 0.f};
        for (int h = 0; h < 128; ++h) {
            float rd = Wd[(d * 128 + h) * 128 + e];
#pragma unroll
            for (int k = 0; k < 4; ++k) acc[k] += rd * wk[og * 4 + k][h];
        }
#pragma unroll
        for (int k = 0; k < 4; ++k) {
            int o = ot * 8 + og * 4 + k;
            Wcat[(size_t)(512 + d * 128 + o) * 128 + e] = f2bf(acc[k]);
        }
        return;
    }
    // pregather: 825 blocks x 8 rows
    int pb = blk - 80;
    int r = pb * 8 + (t >> 5);                // 0..6599
    int fc = t & 31;
    int id = (r < NROWS_IN) ? inp[r] : cand[r - NROWS_IN];
    float4 v = *(const float4*)(et + (size_t)id * 128 + fc * 4);
    if (r < NROWS_IN) *(float4*)(o_emb + (size_t)r * 128 + fc * 4) = v;
    else              *(float4*)(o_cemb + (size_t)(r - NROWS_IN) * 128 + fc * 4) = v;
    ushort4 o;
    o.x = f2bf(v.x); o.y = f2bf(v.y); o.z = f2bf(v.z); o.w = f2bf(v.w);
    *(ushort4*)(Abf + (size_t)r * 128 + fc * 4) = o;
}

// ---------------------------------------------------------------------------
// k_gemm: bf16 MFMA GEMM, 64x64 tile, K=128. One launch covers:
//   gid < 400 : input rows (1600) x Wcat[0..1024)   -> inhid (stride 1024)
//   gid >= 400: cand rows (5000)  x Wcat[512..1024) -> cp    (stride 512)
// 4 waves/block, each wave one 32x32 output via 8x mfma_f32_32x32x16_bf16.
// ---------------------------------------------------------------------------
__global__ __launch_bounds__(256, 4) void k_gemm(const unsigned short* __restrict__ Abf,
                                                 const unsigned short* __restrict__ Wcat,
                                                 float* __restrict__ inhid,
                                                 float* __restrict__ cp) {
    __shared__ __align__(16) unsigned short sa[64 * 128];
    __shared__ __align__(16) unsigned short sb[64 * 128];
    int gid = blockIdx.x;
    int arow0, wrow0, ostride, oc0, orow0, nvalid;
    float* outp;
    if (gid < 400) {
        int rt = gid >> 4, ct = gid & 15;
        arow0 = rt * 64; wrow0 = ct * 64; outp = inhid; ostride = 1024;
        oc0 = ct * 64; orow0 = rt * 64; nvalid = 64;
    } else {
        int g2 = gid - 400;
        int rt = g2 >> 3, ct = g2 & 7;
        arow0 = NROWS_IN + rt * 64; wrow0 = 512 + ct * 64; outp = cp; ostride = 512;
        oc0 = ct * 64; orow0 = rt * 64;
        nvalid = min(64, NROWS_C - rt * 64);
    }
    int t = threadIdx.x;
    // stage A (bf16x8 chunks, XOR swizzle ch^(r&15))
#pragma unroll
    for (int q = 0; q < 4; ++q) {
        int x = t + q * 256;              // 0..1023
        int r = x >> 4, ch = x & 15;
        short8 v = {0, 0, 0, 0, 0, 0, 0, 0};
        if (r < nvalid) v = *(const short8*)(Abf + (size_t)(arow0 + r) * 128 + ch * 8);
        *(short8*)(sa + r * 128 + ((ch ^ (r & 15)) << 3)) = v;
    }
    // stage B
#pragma unroll
    for (int q = 0; q < 4; ++q) {
        int x = t + q * 256;
        int r = x >> 4, ch = x & 15;
        short8 v = *(const short8*)(Wcat + (size_t)(wrow0 + r) * 128 + ch * 8);
        *(short8*)(sb + r * 128 + ((ch ^ (r & 15)) << 3)) = v;
    }
    __syncthreads();
    int w = t >> 6, lane = t & 63;
    int rbase = (w >> 1) * 32, cbase = (w & 1) * 32;
    int lr = lane & 31, g = lane >> 5;
    int arow = rbase + lr;                 // local A row this lane owns
    int bcol = cbase + lr;                 // local B col (Wcat row) this lane owns
    const unsigned short* pa = sa + arow * 128;
    const unsigned short* pb = sb + bcol * 128;
    int axor = arow & 15, bxor = bcol & 15;
    f32x16 acc = {};
#pragma unroll
    for (int ks = 0; ks < 8; ++ks) {
        int chA = ks * 2 + g;              // k-chunk (8 bf16) this lane loads
        short8 a8 = *(const short8*)(pa + ((chA ^ axor) << 3));
        short8 b8 = *(const short8*)(pb + ((chA ^ bxor) << 3));
        acc = __builtin_amdgcn_mfma_f32_32x32x16_bf16(a8, b8, acc, 0, 0, 0);
    }
    // C/D: col = cbase + (lane&31); row = rbase + (r&3) + 8*(r>>2) + 4*(lane>>5)
#pragma unroll
    for (int r = 0; r < 16; ++r) {
        int row_l = rbase + (r & 3) + 8 * (r >> 2) + 4 * g;
        if (row_l < nvalid)
            outp[(size_t)(orow0 + row_l) * ostride + oc0 + cbase + lr] = acc[r];
    }
}

// ---------------------------------------------------------------------------
// k_agg: agg[b*512+j] = log(sum_s exp(inhid[(b*50+s)*1024 + j]))
// ---------------------------------------------------------------------------
__global__ __launch_bounds__(128) void k_agg(const float* __restrict__ hid,
                                             float* __restrict__ agg) {
    int t = blockIdx.x * 128 + threadIdx.x;   // 0..16383
    int b = t >> 9, j = t & 511;
    const float* p = hid + (size_t)b * SS * 1024 + j;
    float s = 0.f;
#pragma unroll 10
    for (int si = 0; si < SS; ++si) s += expf(p[si * 1024]);
    agg[t] = logf(s);
}

// ---------------------------------------------------------------------------
// k_ap_loss: blocks 0..63: ap[bd*128+o] = b[o] + sum_h agg[bd*128+h]*Ws[o*256+h]
//            block 64: demand_sim_loss
// ---------------------------------------------------------------------------
__global__ __launch_bounds__(256) void k_ap_loss(const float* __restrict__ agg,
                                                 const float* __restrict__ Ws,
                                                 const float* __restrict__ bsc,
                                                 float* __restrict__ ap,
                                                 float* __restrict__ loss_out) {
    __shared__ float nrm[128];
    int t = threadIdx.x;
    if (blockIdx.x < 64) {
        int x = blockIdx.x * 256 + t;         // 0..16383
        int bd = x >> 7, o = x & 127;
        const float* a = agg + bd * 128;
        const float* w = Ws + o * 256;
        float acc = bsc[o];
        for (int ch = 0; ch < 32; ++ch) {
            float4 a4 = *(const float4*)(a + ch * 4);
            float4 w4 = *(const float4*)(w + ch * 4);
            acc += a4.x * w4.x + a4.y * w4.y + a4.z * w4.z + a4.w * w4.w;
        }
        ap[x] = acc;
        return;
    }
    if (t < 128) {
        const float* a = agg + t * 128;
        float s = 0.f;
        for (int h = 0; h < 128; ++h) s += a[h] * a[h];
        nrm[t] = fmaxf(sqrtf(s), 1e-8f);
    }
    __syncthreads();
    float lb = 0.f;
    if (t < 32) {
        const float* a = agg + t * 512;
        float i0 = 1.f / nrm[t * 4 + 0], i1 = 1.f / nrm[t * 4 + 1];
        float i2 = 1.f / nrm[t * 4 + 2], i3 = 1.f / nrm[t * 4 + 3];
        for (int h = 0; h < 128; ++h) {
            float u0 = a[h] * i0, u1 = a[128 + h] * i1;
            float u2 = a[256 + h] * i2, u3 = a[384 + h] * i3;
            float v = u0 + u1 + u2 + u3;
            lb += v * v - (u0 * u0 + u1 * u1 + u2 * u2 + u3 * u3);
        }
    }
    for (int off = 32; off; off >>= 1) lb += __shfl_down(lb, off);
    if (t == 0) loss_out[0] = lb / (float)(BB * DDk * (DDk - 1));
}

// ---------------------------------------------------------------------------
// k_score: demand_score[b][d][s] = sum_o w[o]*relu(ap[bd][o]+inhid[bs][512+d*128+o])
// ---------------------------------------------------------------------------
__global__ __launch_bounds__(256) void k_score(const float* __restrict__ ap,
                                               const float* __restrict__ kp,
                                               const float* __restrict__ wsc,
                                               float* __restrict__ out) {
    int t = blockIdx.x * 256 + threadIdx.x;
    if (t >= BB * DDk * SS) return;
    int b = t / (DDk * SS);
    int rem = t - b * (DDk * SS);
    int d = rem / SS, s = rem - d * SS;
    const float* a = ap + (b * DDk + d) * 128;
    const float* k = kp + (size_t)(b * SS + s) * 1024 + 512 + d * 128;
    float acc = 0.f;
    for (int ch = 0; ch < 32; ++ch) {
        float4 a4 = *(const float4*)(a + ch * 4);
        float4 k4 = *(const float4*)(k + ch * 4);
        float4 w4 = *(const float4*)(wsc + ch * 4);
        acc += w4.x * fmaxf(a4.x + k4.x, 0.f) + w4.y * fmaxf(a4.y + k4.y, 0.f)
             + w4.z * fmaxf(a4.z + k4.z, 0.f) + w4.w * fmaxf(a4.w + k4.w, 0.f);
    }
    out[t] = acc;
}

// ---------------------------------------------------------------------------
// k_cand_score: out[b][d][i] = sum_o w[o]*relu(ap[bd][o] + cp[i][d*128+o])
// ---------------------------------------------------------------------------
__global__ __launch_bounds__(256) void k_cand_score(const float* __restrict__ ap,
                                                    const float* __restrict__ cp,
                                                    const float* __restrict__ wsc,
                                                    float* __restrict__ out) {
    __shared__ float sap[32 * 128];
    __shared__ float scp[64 * 128];
    __shared__ float swv[128];
    const int ntiles = (NI + 63) / 64;        // 79
    int d = blockIdx.x / ntiles;
    int tile = blockIdx.x - d * ntiles;
    int i0 = tile * 64;
    int t = threadIdx.x;
    if (t < 128) swv[t] = wsc[t];
#pragma unroll
    for (int q = 0; q < 4; ++q) {             // sap: 32 rows x 32 chunks
        int x = t + q * 256;
        int b = x >> 5, ch = x & 31;
        float4 v = *(const float4*)(ap + (b * 4 + d) * 128 + ch * 4);
        int cs = ch ^ (b & 7);
        *(float4*)(&sap[b * 128 + cs * 4]) = v;
    }
#pragma unroll
    for (int q = 0; q < 8; ++q) {             // scp: 64 rows x 32 chunks
        int x = t + q * 256;
        int il = x >> 5, ch = x & 31;
        int i = i0 + il;
        float4 v = make_float4(0.f, 0.f, 0.f, 0.f);
        if (i < NI) v = *(const float4*)(cp + (size_t)i * 512 + d * 128 + ch * 4);
        int cs = ch ^ (il & 7);
        *(float4*)(&scp[il * 128 + cs * 4]) = v;
    }
    __syncthreads();
    int b = t >> 3, g = t & 7;
    float acc[8] = {0.f, 0.f, 0.f, 0.f, 0.f, 0.f, 0.f, 0.f};
    const float* arow = sap + b * 128;
    for (int ch = 0; ch < 32; ++ch) {
        float4 a4 = *(const float4*)(arow + ((ch ^ (b & 7)) << 2));
        float4 w4 = *(const float4*)(swv + ch * 4);
#pragma unroll
        for (int kk = 0; kk < 8; ++kk) {
            int il = kk * 8 + g;
            float4 c4 = *(const float4*)(&scp[il * 128 + ((ch ^ g) << 2)]);
            acc[kk] += w4.x * fmaxf(a4.x + c4.x, 0.f) + w4.y * fmaxf(a4.y + c4.y, 0.f)
                     + w4.z * fmaxf(a4.z + c4.z, 0.f) + w4.w * fmaxf(a4.w + c4.w, 0.f);
        }
    }
#pragma unroll
    for (int kk = 0; kk < 8; ++kk) {
        int i = i0 + kk * 8 + g;
        if (i < NI) out[(size_t)b * (DDk * NI) + d * NI + i] = acc[kk];
    }
}

// ---------------------------------------------------------------------------
extern "C" void kernel_launch(void* const* d_in, const int* in_sizes, int n_in,
                              void* d_out, int out_size, void* d_ws, size_t ws_size,
                              hipStream_t stream) {
    const int*   inp  = (const int*)d_in[0];
    const int*   cand = (const int*)d_in[1];
    const float* et   = (const float*)d_in[2];
    const float* Wd   = (const float*)d_in[3];
    const float* Ws   = (const float*)d_in[4];
    const float* bsc  = (const float*)d_in[5];
    const float* wsc  = (const float*)d_in[6];

    float* out = (float*)d_out;
    float* o_ds   = out;                  // (B,D,S)    6400
    float* o_dsc  = out + 6400;           // (B,D,I)    640000
    float* o_emb  = out + 646400;         // (B,S,E)    204800
    float* o_cemb = out + 851200;         // (I,E)      640000
    float* o_loss = out + 1491200;        // scalar

    char* wsb = (char*)d_ws;
    unsigned short* Wcat = (unsigned short*)wsb;              // 1024*128 bf16 = 256 KB
    unsigned short* Abf  = (unsigned short*)(wsb + 262144);   // 6600*128 bf16 = 1.65 MB
    float* inhid = (float*)(wsb + 2097152);                   // 1600*1024 f32
    float* cp    = (float*)(wsb + 2097152 + 6553600);         // 5000*512 f32
    float* agg   = (float*)(wsb + 2097152 + 6553600 + 10240000);
    float* ap    = agg + 16384;

    hipLaunchKernelGGL(k_prep, dim3(905), dim3(256), 0, stream,
                       inp, cand, et, Wd, Ws, Wcat, Abf, o_emb, o_cemb);
    hipLaunchKernelGGL(k_gemm, dim3(1032), dim3(256), 0, stream, Abf, Wcat, inhid, cp);
    hipLaunchKernelGGL(k_agg, dim3(128), dim3(128), 0, stream, inhid, agg);
    hipLaunchKernelGGL(k_ap_loss, dim3(65), dim3(256), 0, stream, agg, Ws, bsc, ap, o_loss);
    hipLaunchKernelGGL(k_score, dim3(25), dim3(256), 0, stream, ap, inhid, wsc, o_ds);
    hipLaunchKernelGGL(k_cand_score, dim3(316), dim3(256), 0, stream, ap, cp, wsc, o_dsc);
}

// Round 4
// 50.689 us; speedup vs baseline: 3.4550x; 1.2749x over previous
//
#include <hip/hip_runtime.h>

typedef __attribute__((ext_vector_type(8))) short short8;
typedef __attribute__((ext_vector_type(16))) float f32x16;

#define NROWS_IN 1600
#define NI 5000
#define BB 32
#define DDk 4
#define SS 50

__device__ __forceinline__ unsigned short f2bf(float f) {
    unsigned int u = __float_as_uint(f);
    u = (u + 0x7FFFu + ((u >> 16) & 1u)) >> 16;   // RNE
    return (unsigned short)u;
}

// ---------------------------------------------------------------------------
// k_prep: blk 0..15   : Wd (512x128 f32) -> Wcat[0..512) bf16
//         blk 16..79  : Wcomb[d*128+o][e] = sum_h Wk[o][h]*Wd[d*128+h][e]
//                       -> Wcat[512..1024) bf16
//         blk 80..904 : gather emb rows (input then cand) -> fp32 outs + bf16 Abf
// ---------------------------------------------------------------------------
__global__ __launch_bounds__(256) void k_prep(const int* __restrict__ inp,
                                              const int* __restrict__ cand,
                                              const float* __restrict__ et,
                                              const float* __restrict__ Wd,
                                              const float* __restrict__ Ws,
                                              unsigned short* __restrict__ Wcat,
                                              unsigned short* __restrict__ Abf,
                                              float* __restrict__ o_emb,
                                              float* __restrict__ o_cemb) {
    int t = threadIdx.x;
    int blk = blockIdx.x;
    if (blk < 16) {
        const float4* src = (const float4*)Wd;
#pragma unroll
        for (int q = 0; q < 4; ++q) {
            int i = blk * 256 + t + q * 4096;   // 0..16383 float4s
            float4 v = src[i];
            ushort4 o;
            o.x = f2bf(v.x); o.y = f2bf(v.y); o.z = f2bf(v.z); o.w = f2bf(v.w);
            *(ushort4*)(Wcat + (size_t)i * 4) = o;
        }
        return;
    }
    if (blk < 80) {
        __shared__ float wk[8][128];
        int cb = blk - 16;                    // 0..63
        int d = cb >> 4, ot = cb & 15;
        for (int x = t; x < 8 * 128; x += 256) {
            int ol = x >> 7, h = x & 127;
            wk[ol][h] = Ws[(ot * 8 + ol) * 256 + 128 + h];
        }
        __syncthreads();
        int e = t & 127, og = t >> 7;
        float acc[4] = {0.f, 0.f, 0.f, 0.f};
        for (int h = 0; h < 128; ++h) {
            float rd = Wd[(d * 128 + h) * 128 + e];
#pragma unroll
            for (int k = 0; k < 4; ++k) acc[k] += rd * wk[og * 4 + k][h];
        }
#pragma unroll
        for (int k = 0; k < 4; ++k) {
            int o = ot * 8 + og * 4 + k;
            Wcat[(size_t)(512 + d * 128 + o) * 128 + e] = f2bf(acc[k]);
        }
        return;
    }
    // pregather: 825 blocks x 8 rows
    int pb = blk - 80;
    int r = pb * 8 + (t >> 5);                // 0..6599
    int fc = t & 31;
    int id = (r < NROWS_IN) ? inp[r] : cand[r - NROWS_IN];
    float4 v = *(const float4*)(et + (size_t)id * 128 + fc * 4);
    if (r < NROWS_IN) *(float4*)(o_emb + (size_t)r * 128 + fc * 4) = v;
    else              *(float4*)(o_cemb + (size_t)(r - NROWS_IN) * 128 + fc * 4) = v;
    ushort4 o;
    o.x = f2bf(v.x); o.y = f2bf(v.y); o.z = f2bf(v.z); o.w = f2bf(v.w);
    *(ushort4*)(Abf + (size_t)r * 128 + fc * 4) = o;
}

// ---------------------------------------------------------------------------
// k_gemm_in: input rows (1600) x Wcat (1024 cols) -> inhid, 64x64 tiles.
// ---------------------------------------------------------------------------
__global__ __launch_bounds__(256, 4) void k_gemm_in(const unsigned short* __restrict__ Abf,
                                                    const unsigned short* __restrict__ Wcat,
                                                    float* __restrict__ inhid) {
    __shared__ __align__(16) unsigned short sa[64 * 128];
    __shared__ __align__(16) unsigned short sb[64 * 128];
    int gid = blockIdx.x;               // 0..399
    int rt = gid >> 4, ct = gid & 15;
    int arow0 = rt * 64, wrow0 = ct * 64;
    int t = threadIdx.x;
#pragma unroll
    for (int q = 0; q < 4; ++q) {
        int x = t + q * 256;
        int r = x >> 4, ch = x & 15;
        short8 v = *(const short8*)(Abf + (size_t)(arow0 + r) * 128 + ch * 8);
        *(short8*)(sa + r * 128 + ((ch ^ (r & 15)) << 3)) = v;
    }
#pragma unroll
    for (int q = 0; q < 4; ++q) {
        int x = t + q * 256;
        int r = x >> 4, ch = x & 15;
        short8 v = *(const short8*)(Wcat + (size_t)(wrow0 + r) * 128 + ch * 8);
        *(short8*)(sb + r * 128 + ((ch ^ (r & 15)) << 3)) = v;
    }
    __syncthreads();
    int w = t >> 6, lane = t & 63;
    int rbase = (w >> 1) * 32, cbase = (w & 1) * 32;
    int lr = lane & 31, g = lane >> 5;
    int arow = rbase + lr, bcol = cbase + lr;
    const unsigned short* pa = sa + arow * 128;
    const unsigned short* pb = sb + bcol * 128;
    int axor = arow & 15, bxor = bcol & 15;
    f32x16 acc = {};
#pragma unroll
    for (int ks = 0; ks < 8; ++ks) {
        int chA = ks * 2 + g;
        short8 a8 = *(const short8*)(pa + ((chA ^ axor) << 3));
        short8 b8 = *(const short8*)(pb + ((chA ^ bxor) << 3));
        acc = __builtin_amdgcn_mfma_f32_32x32x16_bf16(a8, b8, acc, 0, 0, 0);
    }
#pragma unroll
    for (int r = 0; r < 16; ++r) {
        int row_l = rbase + (r & 3) + 8 * (r >> 2) + 4 * g;
        inhid[(size_t)(arow0 + row_l) * 1024 + ct * 64 + cbase + lr] = acc[r];
    }
}

// ---------------------------------------------------------------------------
// k_mid: one block per b (512 threads).
//   agg[b][j]  = log(sum_s exp(inhid[(b*50+s)*1024 + j]))      j in [0,512)
//   ap[b][d][o]= bsc[o] + sum_h agg[b][d*128+h]*Ws[o*256+h]
//   o_ds[b][d][s] = sum_o w[o]*relu(ap + inhid[..][512+d*128+o])
// agg, ap also written to ws for the next kernel.
// ---------------------------------------------------------------------------
__global__ __launch_bounds__(512) void k_mid(const float* __restrict__ inhid,
                                             const float* __restrict__ Ws,
                                             const float* __restrict__ bsc,
                                             const float* __restrict__ wsc,
                                             float* __restrict__ aggw,
                                             float* __restrict__ apw,
                                             float* __restrict__ o_ds) {
    __shared__ float sagg[512];
    __shared__ float sap[512];
    int b = blockIdx.x;
    int t = threadIdx.x;
    const float* base = inhid + (size_t)b * SS * 1024;
    {
        float s = 0.f;
#pragma unroll 10
        for (int si = 0; si < SS; ++si) s += expf(base[si * 1024 + t]);
        float a = logf(s);
        sagg[t] = a;
        aggw[b * 512 + t] = a;
    }
    __syncthreads();
    {
        int d = t >> 7, o = t & 127;
        const float* a = sagg + d * 128;
        const float* w = Ws + o * 256;
        float acc = bsc[o];
        for (int ch = 0; ch < 32; ++ch) {
            float4 a4 = *(const float4*)(a + ch * 4);
            float4 w4 = *(const float4*)(w + ch * 4);
            acc += a4.x * w4.x + a4.y * w4.y + a4.z * w4.z + a4.w * w4.w;
        }
        sap[t] = acc;
        apw[b * 512 + t] = acc;
    }
    __syncthreads();
    if (t < DDk * SS) {
        int d = t / SS, s2 = t - d * SS;
        const float* a = sap + d * 128;
        const float* k = base + (size_t)s2 * 1024 + 512 + d * 128;
        float acc = 0.f;
        for (int ch = 0; ch < 32; ++ch) {
            float4 a4 = *(const float4*)(a + ch * 4);
            float4 k4 = *(const float4*)(k + ch * 4);
            float4 w4 = *(const float4*)(wsc + ch * 4);
            acc += w4.x * fmaxf(a4.x + k4.x, 0.f) + w4.y * fmaxf(a4.y + k4.y, 0.f)
                 + w4.z * fmaxf(a4.z + k4.z, 0.f) + w4.w * fmaxf(a4.w + k4.w, 0.f);
        }
        o_ds[b * (DDk * SS) + t] = acc;
    }
}

// ---------------------------------------------------------------------------
// k_cand: blocks 0..315: (64-i tile, d): MFMA cand GEMM -> LDS -> relu score.
//         block 316: demand_sim_loss from aggw.
// LDS: GEMM phase [sa 16K | sw 32K | sap 16K | swv .5K]; score phase overlays
// scp(f32 64x128, 32K) on sa+sw. Total 66 KB -> 2 blocks/CU.
// ---------------------------------------------------------------------------
__global__ __launch_bounds__(256) void k_cand(const unsigned short* __restrict__ Abf,
                                              const unsigned short* __restrict__ Wcat,
                                              const float* __restrict__ apw,
                                              const float* __restrict__ aggw,
                                              const float* __restrict__ wsc,
                                              float* __restrict__ o_dsc,
                                              float* __restrict__ o_loss) {
    __shared__ __align__(16) char lds[66048];
    int gid = blockIdx.x;
    int t = threadIdx.x;
    if (gid >= 316) {                       // ---- loss block ----
        float* nrm = (float*)lds;           // 128 floats
        if (t < 128) {
            const float* a = aggw + t * 128;
            float s = 0.f;
            for (int h = 0; h < 128; ++h) s += a[h] * a[h];
            nrm[t] = fmaxf(sqrtf(s), 1e-8f);
        }
        __syncthreads();
        float lb = 0.f;
        if (t < 32) {
            const float* a = aggw + t * 512;
            float i0 = 1.f / nrm[t * 4 + 0], i1 = 1.f / nrm[t * 4 + 1];
            float i2 = 1.f / nrm[t * 4 + 2], i3 = 1.f / nrm[t * 4 + 3];
            for (int h = 0; h < 128; ++h) {
                float u0 = a[h] * i0, u1 = a[128 + h] * i1;
                float u2 = a[256 + h] * i2, u3 = a[384 + h] * i3;
                float v = u0 + u1 + u2 + u3;
                lb += v * v - (u0 * u0 + u1 * u1 + u2 * u2 + u3 * u3);
            }
        }
        for (int off = 32; off; off >>= 1) lb += __shfl_down(lb, off);
        if (t == 0) o_loss[0] = lb / (float)(BB * DDk * (DDk - 1));
        return;
    }
    unsigned short* sa  = (unsigned short*)lds;              // 64x128 bf16
    unsigned short* sw  = (unsigned short*)(lds + 16384);    // 128x128 bf16
    float*          scp = (float*)lds;                       // 64x128 f32 (overlay)
    float*          sap = (float*)(lds + 49152);             // 32x128 f32
    float*          swv = (float*)(lds + 65536);             // 128 f32

    int tile = gid >> 2, d = gid & 3;
    int i0 = tile * 64;
    // stage sa: cand rows (zero-pad last tile)
#pragma unroll
    for (int q = 0; q < 4; ++q) {
        int x = t + q * 256;
        int r = x >> 4, ch = x & 15;
        short8 v = {0, 0, 0, 0, 0, 0, 0, 0};
        if (i0 + r < NI) v = *(const short8*)(Abf + (size_t)(NROWS_IN + i0 + r) * 128 + ch * 8);
        *(short8*)(sa + r * 128 + ((ch ^ (r & 15)) << 3)) = v;
    }
    // stage sw: Wcomb_d (Wcat rows 512+d*128 .. +128)
#pragma unroll
    for (int q = 0; q < 8; ++q) {
        int x = t + q * 256;
        int r = x >> 4, ch = x & 15;
        short8 v = *(const short8*)(Wcat + (size_t)(512 + d * 128 + r) * 128 + ch * 8);
        *(short8*)(sw + r * 128 + ((ch ^ (r & 15)) << 3)) = v;
    }
    // stage sap (ap rows for this d) + swv
    if (t < 128) swv[t] = wsc[t];
#pragma unroll
    for (int q = 0; q < 4; ++q) {
        int x = t + q * 256;                // 1024 float4s = 32x128 f32
        int b = x >> 5, ch = x & 31;
        float4 v = *(const float4*)(apw + (size_t)(b * 4 + d) * 128 + ch * 4);
        *(float4*)(sap + b * 128 + ((ch ^ (b & 7)) << 2)) = v;
    }
    __syncthreads();
    // GEMM: wave w: rows (w&1)*32, cols (w>>1)*64 (two 32x32 tiles)
    int w = t >> 6, lane = t & 63;
    int rbase = (w & 1) * 32, cbase = (w >> 1) * 64;
    int lr = lane & 31, g = lane >> 5;
    int arow = rbase + lr;
    int bcol0 = cbase + lr, bcol1 = cbase + 32 + lr;
    const unsigned short* pa  = sa + arow * 128;
    const unsigned short* pb0 = sw + bcol0 * 128;
    const unsigned short* pb1 = sw + bcol1 * 128;
    int axor = arow & 15, b0x = bcol0 & 15, b1x = bcol1 & 15;
    f32x16 acc0 = {}, acc1 = {};
#pragma unroll
    for (int ks = 0; ks < 8; ++ks) {
        int chA = ks * 2 + g;
        short8 a8 = *(const short8*)(pa  + ((chA ^ axor) << 3));
        short8 b8 = *(const short8*)(pb0 + ((chA ^ b0x) << 3));
        short8 c8 = *(const short8*)(pb1 + ((chA ^ b1x) << 3));
        acc0 = __builtin_amdgcn_mfma_f32_32x32x16_bf16(a8, b8, acc0, 0, 0, 0);
        acc1 = __builtin_amdgcn_mfma_f32_32x32x16_bf16(a8, c8, acc1, 0, 0, 0);
    }
    __syncthreads();                        // done reading sa/sw
    // scatter cp tile into scp (swizzled f32): element (row,col) at
    // row*128 + ((col>>2 ^ (row&7))<<2) + (col&3)
#pragma unroll
    for (int r = 0; r < 16; ++r) {
        int row = rbase + (r & 3) + 8 * (r >> 2) + 4 * g;
        int c0 = cbase + lr, c1 = cbase + 32 + lr;
        scp[row * 128 + ((((c0 >> 2) ^ (row & 7)) << 2) | (c0 & 3))] = acc0[r];
        scp[row * 128 + ((((c1 >> 2) ^ (row & 7)) << 2) | (c1 & 3))] = acc1[r];
    }
    __syncthreads();
    // score: thread (b = t>>3, gg = t&7) -> 8 i's
    int b = t >> 3, gg = t & 7;
    int bx = b & 7;
    float acc[8] = {0.f, 0.f, 0.f, 0.f, 0.f, 0.f, 0.f, 0.f};
    const float* arow2 = sap + b * 128;
    for (int ch = 0; ch < 32; ++ch) {
        float4 a4 = *(const float4*)(arow2 + ((ch ^ bx) << 2));
        float4 w4 = *(const float4*)(swv + ch * 4);
#pragma unroll
        for (int kk = 0; kk < 8; ++kk) {
            int il = kk * 8 + gg;
            float4 c4 = *(const float4*)(&scp[il * 128 + ((ch ^ (il & 7)) << 2)]);
            acc[kk] += w4.x * fmaxf(a4.x + c4.x, 0.f) + w4.y * fmaxf(a4.y + c4.y, 0.f)
                     + w4.z * fmaxf(a4.z + c4.z, 0.f) + w4.w * fmaxf(a4.w + c4.w, 0.f);
        }
    }
#pragma unroll
    for (int kk = 0; kk < 8; ++kk) {
        int i = i0 + kk * 8 + gg;
        if (i < NI) o_dsc[(size_t)b * (DDk * NI) + d * NI + i] = acc[kk];
    }
}

// ---------------------------------------------------------------------------
extern "C" void kernel_launch(void* const* d_in, const int* in_sizes, int n_in,
                              void* d_out, int out_size, void* d_ws, size_t ws_size,
                              hipStream_t stream) {
    const int*   inp  = (const int*)d_in[0];
    const int*   cand = (const int*)d_in[1];
    const float* et   = (const float*)d_in[2];
    const float* Wd   = (const float*)d_in[3];
    const float* Ws   = (const float*)d_in[4];
    const float* bsc  = (const float*)d_in[5];
    const float* wsc  = (const float*)d_in[6];

    float* out = (float*)d_out;
    float* o_ds   = out;                  // (B,D,S)    6400
    float* o_dsc  = out + 6400;           // (B,D,I)    640000
    float* o_emb  = out + 646400;         // (B,S,E)    204800
    float* o_cemb = out + 851200;         // (I,E)      640000
    float* o_loss = out + 1491200;        // scalar

    char* wsb = (char*)d_ws;
    unsigned short* Wcat = (unsigned short*)wsb;              // 1024x128 bf16
    unsigned short* Abf  = (unsigned short*)(wsb + 262144);   // 6600x128 bf16
    float* inhid = (float*)(wsb + 2097152);                   // 1600x1024 f32
    float* aggw  = (float*)(wsb + 2097152 + 6553600);         // 16384 f32
    float* apw   = aggw + 16384;                              // 16384 f32

    hipLaunchKernelGGL(k_prep, dim3(905), dim3(256), 0, stream,
                       inp, cand, et, Wd, Ws, Wcat, Abf, o_emb, o_cemb);
    hipLaunchKernelGGL(k_gemm_in, dim3(400), dim3(256), 0, stream, Abf, Wcat, inhid);
    hipLaunchKernelGGL(k_mid, dim3(BB), dim3(512), 0, stream,
                       inhid, Ws, bsc, wsc, aggw, apw, o_ds);
    hipLaunchKernelGGL(k_cand, dim3(317), dim3(256), 0, stream,
                       Abf, Wcat, apw, aggw, wsc, o_dsc, o_loss);
}

// Round 5
// 38.622 us; speedup vs baseline: 4.5344x; 1.3124x over previous
//
#include <hip/hip_runtime.h>

typedef __attribute__((ext_vector_type(8))) short short8;
typedef __attribute__((ext_vector_type(16))) float f32x16;

#define NROWS_IN 1600
#define NI 5000
#define BB 32
#define DDk 4
#define SS 50

__device__ __forceinline__ unsigned short f2bf(float f) {
    unsigned int u = __float_as_uint(f);
    u = (u + 0x7FFFu + ((u >> 16) & 1u)) >> 16;   // RNE
    return (unsigned short)u;
}
__device__ __forceinline__ float b2f(unsigned short u) {
    return __uint_as_float(((unsigned int)u) << 16);
}

// ---------------------------------------------------------------------------
// k_prep: blk 0..15   : Wd (512x128 f32) -> Wcat[0..512) bf16
//         blk 16..79  : Wcomb[d*128+o][e] = sum_h Wk[o][h]*Wd[d*128+h][e]
//                       (Wd_d tile staged in LDS) -> Wcat[512..1024) bf16
//         blk 80..904 : gather emb rows (input then cand) -> fp32 outs + bf16 Abf
// ---------------------------------------------------------------------------
__global__ __launch_bounds__(256) void k_prep(const int* __restrict__ inp,
                                              const int* __restrict__ cand,
                                              const float* __restrict__ et,
                                              const float* __restrict__ Wd,
                                              const float* __restrict__ Ws,
                                              unsigned short* __restrict__ Wcat,
                                              unsigned short* __restrict__ Abf,
                                              float* __restrict__ o_emb,
                                              float* __restrict__ o_cemb) {
    int t = threadIdx.x;
    int blk = blockIdx.x;
    if (blk < 16) {
        const float4* src = (const float4*)Wd;
#pragma unroll
        for (int q = 0; q < 4; ++q) {
            int i = blk * 256 + t + q * 4096;   // 0..16383 float4s
            float4 v = src[i];
            ushort4 o;
            o.x = f2bf(v.x); o.y = f2bf(v.y); o.z = f2bf(v.z); o.w = f2bf(v.w);
            *(ushort4*)(Wcat + (size_t)i * 4) = o;
        }
        return;
    }
    if (blk < 80) {
        __shared__ __align__(16) float sdw[128 * 128];   // Wd_d tile [h][e]
        __shared__ float wk[8][128];
        int cb = blk - 16;                    // 0..63
        int d = cb >> 4, ot = cb & 15;
        const float4* src = (const float4*)(Wd + (size_t)d * 128 * 128);
#pragma unroll
        for (int q = 0; q < 16; ++q) {
            int i = t + q * 256;              // 4096 float4s
            *(float4*)(&sdw[i * 4]) = src[i];
        }
        for (int x = t; x < 8 * 128; x += 256) {
            int ol = x >> 7, h = x & 127;
            wk[ol][h] = Ws[(ot * 8 + ol) * 256 + 128 + h];
        }
        __syncthreads();
        int e = t & 127, og = t >> 7;
        float acc[4] = {0.f, 0.f, 0.f, 0.f};
        for (int h = 0; h < 128; ++h) {
            float rd = sdw[h * 128 + e];
#pragma unroll
            for (int k = 0; k < 4; ++k) acc[k] += rd * wk[og * 4 + k][h];
        }
#pragma unroll
        for (int k = 0; k < 4; ++k) {
            int o = ot * 8 + og * 4 + k;
            Wcat[(size_t)(512 + d * 128 + o) * 128 + e] = f2bf(acc[k]);
        }
        return;
    }
    // pregather: 825 blocks x 8 rows
    int pb = blk - 80;
    int r = pb * 8 + (t >> 5);                // 0..6599
    int fc = t & 31;
    int id = (r < NROWS_IN) ? inp[r] : cand[r - NROWS_IN];
    float4 v = *(const float4*)(et + (size_t)id * 128 + fc * 4);
    if (r < NROWS_IN) *(float4*)(o_emb + (size_t)r * 128 + fc * 4) = v;
    else              *(float4*)(o_cemb + (size_t)(r - NROWS_IN) * 128 + fc * 4) = v;
    ushort4 o;
    o.x = f2bf(v.x); o.y = f2bf(v.y); o.z = f2bf(v.z); o.w = f2bf(v.w);
    *(ushort4*)(Abf + (size_t)r * 128 + fc * 4) = o;
}

// ---------------------------------------------------------------------------
// k_gemm_in: input rows (1600) x Wcat (1024 cols) -> inhid (bf16), 64x128 tiles.
// Wave w: rows (w&1)*32, cols (w>>1)*64 .. +64 (two 32x32 accs).
// ---------------------------------------------------------------------------
__global__ __launch_bounds__(256) void k_gemm_in(const unsigned short* __restrict__ Abf,
                                                 const unsigned short* __restrict__ Wcat,
                                                 unsigned short* __restrict__ inhid) {
    __shared__ __align__(16) unsigned short sa[64 * 128];
    __shared__ __align__(16) unsigned short sb[128 * 128];
    int gid = blockIdx.x;               // 0..199
    int rt = gid >> 3, ct = gid & 7;
    int arow0 = rt * 64, wrow0 = ct * 128;
    int t = threadIdx.x;
#pragma unroll
    for (int q = 0; q < 4; ++q) {
        int x = t + q * 256;
        int r = x >> 4, ch = x & 15;
        short8 v = *(const short8*)(Abf + (size_t)(arow0 + r) * 128 + ch * 8);
        *(short8*)(sa + r * 128 + ((ch ^ (r & 15)) << 3)) = v;
    }
#pragma unroll
    for (int q = 0; q < 8; ++q) {
        int x = t + q * 256;
        int r = x >> 4, ch = x & 15;
        short8 v = *(const short8*)(Wcat + (size_t)(wrow0 + r) * 128 + ch * 8);
        *(short8*)(sb + r * 128 + ((ch ^ (r & 15)) << 3)) = v;
    }
    __syncthreads();
    int w = t >> 6, lane = t & 63;
    int rbase = (w & 1) * 32, cbase = (w >> 1) * 64;
    int lr = lane & 31, g = lane >> 5;
    int arow = rbase + lr;
    int bcol0 = cbase + lr, bcol1 = cbase + 32 + lr;
    const unsigned short* pa  = sa + arow * 128;
    const unsigned short* pb0 = sb + bcol0 * 128;
    const unsigned short* pb1 = sb + bcol1 * 128;
    int axor = arow & 15, b0x = bcol0 & 15, b1x = bcol1 & 15;
    f32x16 acc0 = {}, acc1 = {};
#pragma unroll
    for (int ks = 0; ks < 8; ++ks) {
        int chA = ks * 2 + g;
        short8 a8 = *(const short8*)(pa  + ((chA ^ axor) << 3));
        short8 b8 = *(const short8*)(pb0 + ((chA ^ b0x) << 3));
        short8 c8 = *(const short8*)(pb1 + ((chA ^ b1x) << 3));
        acc0 = __builtin_amdgcn_mfma_f32_32x32x16_bf16(a8, b8, acc0, 0, 0, 0);
        acc1 = __builtin_amdgcn_mfma_f32_32x32x16_bf16(a8, c8, acc1, 0, 0, 0);
    }
#pragma unroll
    for (int r = 0; r < 16; ++r) {
        int row_l = rbase + (r & 3) + 8 * (r >> 2) + 4 * g;
        size_t base = (size_t)(arow0 + row_l) * 1024 + wrow0;
        inhid[base + cbase + lr]      = f2bf(acc0[r]);
        inhid[base + cbase + 32 + lr] = f2bf(acc1[r]);
    }
}

// ---------------------------------------------------------------------------
// k_mid: one block per (b,d)  (128 blocks x 256 threads). All phases d-local.
//   agg[b][d*128+j] = log(sum_s exp(hid[b,s,d*128+j]))
//   ap[b][d][o]     = bsc[o] + sum_h agg[b][d*128+h]*Ws[o*256+h]
//   o_ds[b][d][s]   = sum_o wsc[o]*relu(ap + kp[b,s,512+d*128+o])
// ---------------------------------------------------------------------------
__global__ __launch_bounds__(256) void k_mid(const unsigned short* __restrict__ inhid,
                                             const float* __restrict__ Ws,
                                             const float* __restrict__ bsc,
                                             const float* __restrict__ wsc,
                                             float* __restrict__ aggw,
                                             float* __restrict__ apw,
                                             float* __restrict__ o_ds) {
    __shared__ __align__(16) float sexp[2][128];
    __shared__ __align__(16) float sagg[128];
    __shared__ __align__(16) float sap[128];
    __shared__ float spart[200];
    int b = blockIdx.x >> 2, d = blockIdx.x & 3;
    int t = threadIdx.x;
    // phase 1: partial exp-sums (two s-halves)
    {
        int sg = t >> 7, j = t & 127;
        const unsigned short* p = inhid + (size_t)(b * SS + sg * 25) * 1024 + d * 128 + j;
        float s = 0.f;
#pragma unroll 5
        for (int si = 0; si < 25; ++si) s += expf(b2f(p[si * 1024]));
        sexp[sg][j] = s;
    }
    __syncthreads();
    if (t < 128) {
        float a = logf(sexp[0][t] + sexp[1][t]);
        sagg[t] = a;
        aggw[b * 512 + d * 128 + t] = a;
    }
    __syncthreads();
    // phase 2: ap
    if (t < 128) {
        const float* w = Ws + t * 256;
        float acc = bsc[t];
        for (int ch = 0; ch < 32; ++ch) {
            float4 a4 = *(const float4*)(sagg + ch * 4);
            float4 w4 = *(const float4*)(w + ch * 4);
            acc += a4.x * w4.x + a4.y * w4.y + a4.z * w4.z + a4.w * w4.w;
        }
        sap[t] = acc;
        apw[(b * DDk + d) * 128 + t] = acc;
    }
    __syncthreads();
    // phase 3: demand_score, thread (s = t>>2, oq = t&3) -> 32-o partial
    if (t < 200) {
        int s = t >> 2, oq = t & 3;
        const unsigned short* kpp = inhid + (size_t)(b * SS + s) * 1024 + 512 + d * 128 + oq * 32;
        float acc = 0.f;
#pragma unroll
        for (int c = 0; c < 8; ++c) {
            float4 a4 = *(const float4*)(sap + oq * 32 + c * 4);
            float4 w4 = *(const float4*)(wsc + oq * 32 + c * 4);
            ushort4 k4 = *(const ushort4*)(kpp + c * 4);
            acc += w4.x * fmaxf(a4.x + b2f(k4.x), 0.f) + w4.y * fmaxf(a4.y + b2f(k4.y), 0.f)
                 + w4.z * fmaxf(a4.z + b2f(k4.z), 0.f) + w4.w * fmaxf(a4.w + b2f(k4.w), 0.f);
        }
        spart[t] = acc;
    }
    __syncthreads();
    if (t < SS) {
        float v = spart[t * 4] + spart[t * 4 + 1] + spart[t * 4 + 2] + spart[t * 4 + 3];
        o_ds[b * (DDk * SS) + d * SS + t] = v;
    }
}

// ---------------------------------------------------------------------------
// k_cand: blocks 0..315: (64-i tile, d): MFMA cand GEMM -> LDS -> relu score.
//         block 316: demand_sim_loss from aggw.
// ---------------------------------------------------------------------------
__global__ __launch_bounds__(256) void k_cand(const unsigned short* __restrict__ Abf,
                                              const unsigned short* __restrict__ Wcat,
                                              const float* __restrict__ apw,
                                              const float* __restrict__ aggw,
                                              const float* __restrict__ wsc,
                                              float* __restrict__ o_dsc,
                                              float* __restrict__ o_loss) {
    __shared__ __align__(16) char lds[66048];
    int gid = blockIdx.x;
    int t = threadIdx.x;
    if (gid >= 316) {                       // ---- loss block ----
        float* nrm = (float*)lds;           // 128 floats
        if (t < 128) {
            const float* a = aggw + t * 128;
            float s = 0.f;
            for (int h = 0; h < 128; ++h) s += a[h] * a[h];
            nrm[t] = fmaxf(sqrtf(s), 1e-8f);
        }
        __syncthreads();
        float lb = 0.f;
        if (t < 32) {
            const float* a = aggw + t * 512;
            float i0 = 1.f / nrm[t * 4 + 0], i1 = 1.f / nrm[t * 4 + 1];
            float i2 = 1.f / nrm[t * 4 + 2], i3 = 1.f / nrm[t * 4 + 3];
            for (int h = 0; h < 128; ++h) {
                float u0 = a[h] * i0, u1 = a[128 + h] * i1;
                float u2 = a[256 + h] * i2, u3 = a[384 + h] * i3;
                float v = u0 + u1 + u2 + u3;
                lb += v * v - (u0 * u0 + u1 * u1 + u2 * u2 + u3 * u3);
            }
        }
        for (int off = 32; off; off >>= 1) lb += __shfl_down(lb, off);
        if (t == 0) o_loss[0] = lb / (float)(BB * DDk * (DDk - 1));
        return;
    }
    unsigned short* sa  = (unsigned short*)lds;              // 64x128 bf16
    unsigned short* sw  = (unsigned short*)(lds + 16384);    // 128x128 bf16
    float*          scp = (float*)lds;                       // 64x128 f32 (overlay)
    float*          sap = (float*)(lds + 49152);             // 32x128 f32
    float*          swv = (float*)(lds + 65536);             // 128 f32

    int tile = gid >> 2, d = gid & 3;
    int i0 = tile * 64;
    // stage sa: cand rows (zero-pad last tile)
#pragma unroll
    for (int q = 0; q < 4; ++q) {
        int x = t + q * 256;
        int r = x >> 4, ch = x & 15;
        short8 v = {0, 0, 0, 0, 0, 0, 0, 0};
        if (i0 + r < NI) v = *(const short8*)(Abf + (size_t)(NROWS_IN + i0 + r) * 128 + ch * 8);
        *(short8*)(sa + r * 128 + ((ch ^ (r & 15)) << 3)) = v;
    }
    // stage sw: Wcomb_d (Wcat rows 512+d*128 .. +128)
#pragma unroll
    for (int q = 0; q < 8; ++q) {
        int x = t + q * 256;
        int r = x >> 4, ch = x & 15;
        short8 v = *(const short8*)(Wcat + (size_t)(512 + d * 128 + r) * 128 + ch * 8);
        *(short8*)(sw + r * 128 + ((ch ^ (r & 15)) << 3)) = v;
    }
    // stage sap (ap rows for this d) + swv
    if (t < 128) swv[t] = wsc[t];
#pragma unroll
    for (int q = 0; q < 4; ++q) {
        int x = t + q * 256;                // 1024 float4s = 32x128 f32
        int b = x >> 5, ch = x & 31;
        float4 v = *(const float4*)(apw + (size_t)(b * 4 + d) * 128 + ch * 4);
        *(float4*)(sap + b * 128 + ((ch ^ (b & 7)) << 2)) = v;
    }
    __syncthreads();
    // GEMM: wave w: rows (w&1)*32, cols (w>>1)*64 (two 32x32 tiles)
    int w = t >> 6, lane = t & 63;
    int rbase = (w & 1) * 32, cbase = (w >> 1) * 64;
    int lr = lane & 31, g = lane >> 5;
    int arow = rbase + lr;
    int bcol0 = cbase + lr, bcol1 = cbase + 32 + lr;
    const unsigned short* pa  = sa + arow * 128;
    const unsigned short* pb0 = sw + bcol0 * 128;
    const unsigned short* pb1 = sw + bcol1 * 128;
    int axor = arow & 15, b0x = bcol0 & 15, b1x = bcol1 & 15;
    f32x16 acc0 = {}, acc1 = {};
#pragma unroll
    for (int ks = 0; ks < 8; ++ks) {
        int chA = ks * 2 + g;
        short8 a8 = *(const short8*)(pa  + ((chA ^ axor) << 3));
        short8 b8 = *(const short8*)(pb0 + ((chA ^ b0x) << 3));
        short8 c8 = *(const short8*)(pb1 + ((chA ^ b1x) << 3));
        acc0 = __builtin_amdgcn_mfma_f32_32x32x16_bf16(a8, b8, acc0, 0, 0, 0);
        acc1 = __builtin_amdgcn_mfma_f32_32x32x16_bf16(a8, c8, acc1, 0, 0, 0);
    }
    __syncthreads();                        // done reading sa/sw
    // scatter cp tile into scp (swizzled f32)
#pragma unroll
    for (int r = 0; r < 16; ++r) {
        int row = rbase + (r & 3) + 8 * (r >> 2) + 4 * g;
        int c0 = cbase + lr, c1 = cbase + 32 + lr;
        scp[row * 128 + ((((c0 >> 2) ^ (row & 7)) << 2) | (c0 & 3))] = acc0[r];
        scp[row * 128 + ((((c1 >> 2) ^ (row & 7)) << 2) | (c1 & 3))] = acc1[r];
    }
    __syncthreads();
    // score: thread (b = t>>3, gg = t&7) -> 8 i's
    int b = t >> 3, gg = t & 7;
    int bx = b & 7;
    float acc[8] = {0.f, 0.f, 0.f, 0.f, 0.f, 0.f, 0.f, 0.f};
    const float* arow2 = sap + b * 128;
    for (int ch = 0; ch < 32; ++ch) {
        float4 a4 = *(const float4*)(arow2 + ((ch ^ bx) << 2));
        float4 w4 = *(const float4*)(swv + ch * 4);
#pragma unroll
        for (int kk = 0; kk < 8; ++kk) {
            int il = kk * 8 + gg;
            float4 c4 = *(const float4*)(&scp[il * 128 + ((ch ^ (il & 7)) << 2)]);
            acc[kk] += w4.x * fmaxf(a4.x + c4.x, 0.f) + w4.y * fmaxf(a4.y + c4.y, 0.f)
                     + w4.z * fmaxf(a4.z + c4.z, 0.f) + w4.w * fmaxf(a4.w + c4.w, 0.f);
        }
    }
#pragma unroll
    for (int kk = 0; kk < 8; ++kk) {
        int i = i0 + kk * 8 + gg;
        if (i < NI) o_dsc[(size_t)b * (DDk * NI) + d * NI + i] = acc[kk];
    }
}

// ---------------------------------------------------------------------------
extern "C" void kernel_launch(void* const* d_in, const int* in_sizes, int n_in,
                              void* d_out, int out_size, void* d_ws, size_t ws_size,
                              hipStream_t stream) {
    const int*   inp  = (const int*)d_in[0];
    const int*   cand = (const int*)d_in[1];
    const float* et   = (const float*)d_in[2];
    const float* Wd   = (const float*)d_in[3];
    const float* Ws   = (const float*)d_in[4];
    const float* bsc  = (const float*)d_in[5];
    const float* wsc  = (const float*)d_in[6];

    float* out = (float*)d_out;
    float* o_ds   = out;                  // (B,D,S)    6400
    float* o_dsc  = out + 6400;           // (B,D,I)    640000
    float* o_emb  = out + 646400;         // (B,S,E)    204800
    float* o_cemb = out + 851200;         // (I,E)      640000
    float* o_loss = out + 1491200;        // scalar

    char* wsb = (char*)d_ws;
    unsigned short* Wcat  = (unsigned short*)wsb;              // 1024x128 bf16
    unsigned short* Abf   = (unsigned short*)(wsb + 262144);   // 6600x128 bf16
    unsigned short* inhid = (unsigned short*)(wsb + 2097152);  // 1600x1024 bf16
    float* aggw = (float*)(wsb + 2097152 + 3276800);           // 16384 f32
    float* apw  = aggw + 16384;                                // 16384 f32

    hipLaunchKernelGGL(k_prep, dim3(905), dim3(256), 0, stream,
                       inp, cand, et, Wd, Ws, Wcat, Abf, o_emb, o_cemb);
    hipLaunchKernelGGL(k_gemm_in, dim3(200), dim3(256), 0, stream, Abf, Wcat, inhid);
    hipLaunchKernelGGL(k_mid, dim3(128), dim3(256), 0, stream,
                       inhid, Ws, bsc, wsc, aggw, apw, o_ds);
    hipLaunchKernelGGL(k_cand, dim3(317), dim3(256), 0, stream,
                       Abf, Wcat, apw, aggw, wsc, o_dsc, o_loss);
}

// Round 6
// 37.012 us; speedup vs baseline: 4.7317x; 1.0435x over previous
//
#include <hip/hip_runtime.h>

typedef __attribute__((ext_vector_type(8))) short short8;
typedef __attribute__((ext_vector_type(16))) float f32x16;

#define NROWS_IN 1600
#define NI 5000
#define BB 32
#define DDk 4
#define SS 50

__device__ __forceinline__ unsigned short f2bf(float f) {
    unsigned int u = __float_as_uint(f);
    u = (u + 0x7FFFu + ((u >> 16) & 1u)) >> 16;   // RNE
    return (unsigned short)u;
}
__device__ __forceinline__ float b2f(unsigned short u) {
    return __uint_as_float(((unsigned int)u) << 16);
}

// ---------------------------------------------------------------------------
// k_prep: blk 0..15   : Wd (512x128 f32) -> Wcat[0..512) bf16
//         blk 16..79  : Wcomb[d*128+o][e] = sum_h Wk[o][h]*Wd[d*128+h][e]
//                       (Wd_d tile staged in LDS) -> Wcat[512..1024) bf16
//         blk 80..904 : gather emb rows (input then cand) -> fp32 outs + bf16 Abf
// ---------------------------------------------------------------------------
__global__ __launch_bounds__(256) void k_prep(const int* __restrict__ inp,
                                              const int* __restrict__ cand,
                                              const float* __restrict__ et,
                                              const float* __restrict__ Wd,
                                              const float* __restrict__ Ws,
                                              unsigned short* __restrict__ Wcat,
                                              unsigned short* __restrict__ Abf,
                                              float* __restrict__ o_emb,
                                              float* __restrict__ o_cemb) {
    int t = threadIdx.x;
    int blk = blockIdx.x;
    if (blk < 16) {
        const float4* src = (const float4*)Wd;
#pragma unroll
        for (int q = 0; q < 4; ++q) {
            int i = blk * 256 + t + q * 4096;   // 0..16383 float4s
            float4 v = src[i];
            ushort4 o;
            o.x = f2bf(v.x); o.y = f2bf(v.y); o.z = f2bf(v.z); o.w = f2bf(v.w);
            *(ushort4*)(Wcat + (size_t)i * 4) = o;
        }
        return;
    }
    if (blk < 80) {
        __shared__ __align__(16) float sdw[128 * 128];   // Wd_d tile [h][e]
        __shared__ float wk[8][128];
        int cb = blk - 16;                    // 0..63
        int d = cb >> 4, ot = cb & 15;
        const float4* src = (const float4*)(Wd + (size_t)d * 128 * 128);
#pragma unroll
        for (int q = 0; q < 16; ++q) {
            int i = t + q * 256;              // 4096 float4s
            *(float4*)(&sdw[i * 4]) = src[i];
        }
        for (int x = t; x < 8 * 128; x += 256) {
            int ol = x >> 7, h = x & 127;
            wk[ol][h] = Ws[(ot * 8 + ol) * 256 + 128 + h];
        }
        __syncthreads();
        int e = t & 127, og = t >> 7;
        float acc[4] = {0.f, 0.f, 0.f, 0.f};
        for (int h = 0; h < 128; ++h) {
            float rd = sdw[h * 128 + e];
#pragma unroll
            for (int k = 0; k < 4; ++k) acc[k] += rd * wk[og * 4 + k][h];
        }
#pragma unroll
        for (int k = 0; k < 4; ++k) {
            int o = ot * 8 + og * 4 + k;
            Wcat[(size_t)(512 + d * 128 + o) * 128 + e] = f2bf(acc[k]);
        }
        return;
    }
    // pregather: 825 blocks x 8 rows
    int pb = blk - 80;
    int r = pb * 8 + (t >> 5);                // 0..6599
    int fc = t & 31;
    int id = (r < NROWS_IN) ? inp[r] : cand[r - NROWS_IN];
    float4 v = *(const float4*)(et + (size_t)id * 128 + fc * 4);
    if (r < NROWS_IN) *(float4*)(o_emb + (size_t)r * 128 + fc * 4) = v;
    else              *(float4*)(o_cemb + (size_t)(r - NROWS_IN) * 128 + fc * 4) = v;
    ushort4 o;
    o.x = f2bf(v.x); o.y = f2bf(v.y); o.z = f2bf(v.z); o.w = f2bf(v.w);
    *(ushort4*)(Abf + (size_t)r * 128 + fc * 4) = o;
}

// ---------------------------------------------------------------------------
// k_fused_mid: one block per (b,d), 128 blocks x 256 threads.
//   MFMA1: hidden[s][h] = emb[b,s,:] @ Wd_d^T       (exp-sums from regs)
//   MFMA2: kp[s][o]     = emb[b,s,:] @ Wcomb_d^T    (scattered to LDS)
//   agg -> ap -> demand_score, all in-block. No hidden/kp global round-trip.
// LDS: [sa 16K][sb 32K][sred 2.5K][sagg][sap][spart]; skp(32K) overlays sa+sb
// after both MFMAs.
// ---------------------------------------------------------------------------
__global__ __launch_bounds__(256) void k_fused_mid(const unsigned short* __restrict__ Abf,
                                                   const unsigned short* __restrict__ Wcat,
                                                   const float* __restrict__ Ws,
                                                   const float* __restrict__ bsc,
                                                   const float* __restrict__ wsc,
                                                   float* __restrict__ aggw,
                                                   float* __restrict__ apw,
                                                   float* __restrict__ o_ds) {
    __shared__ __align__(16) char lds[53536];
    unsigned short* sa   = (unsigned short*)lds;             // 64x128 bf16
    unsigned short* sb   = (unsigned short*)(lds + 16384);   // 128x128 bf16
    float*          skp  = (float*)lds;                      // 64x128 f32 (overlay)
    float*          sred = (float*)(lds + 49152);            // 128x5
    float*          sagg = (float*)(lds + 51712);            // 128
    float*          sap  = (float*)(lds + 52224);            // 128
    float*          spart= (float*)(lds + 52736);            // 200

    int b = blockIdx.x >> 2, d = blockIdx.x & 3;
    int t = threadIdx.x;
    // stage sa: emb rows b*50..+50, zero-pad to 64
#pragma unroll
    for (int q = 0; q < 4; ++q) {
        int x = t + q * 256;
        int r = x >> 4, ch = x & 15;
        short8 v = {0, 0, 0, 0, 0, 0, 0, 0};
        if (r < SS) v = *(const short8*)(Abf + (size_t)(b * SS + r) * 128 + ch * 8);
        *(short8*)(sa + r * 128 + ((ch ^ (r & 15)) << 3)) = v;
    }
    // stage sb: Wd_d = Wcat rows d*128..+128
#pragma unroll
    for (int q = 0; q < 8; ++q) {
        int x = t + q * 256;
        int r = x >> 4, ch = x & 15;
        short8 v = *(const short8*)(Wcat + (size_t)(d * 128 + r) * 128 + ch * 8);
        *(short8*)(sb + r * 128 + ((ch ^ (r & 15)) << 3)) = v;
    }
    __syncthreads();

    int w = t >> 6, lane = t & 63;
    int lr = lane & 31, g = lane >> 5;
    int rt = w & 1, ct = w >> 1;
    int arow = rt * 32 + lr;
    int bcol0 = ct * 64 + lr, bcol1 = ct * 64 + 32 + lr;
    const unsigned short* pa  = sa + arow * 128;
    const unsigned short* pb0 = sb + bcol0 * 128;
    const unsigned short* pb1 = sb + bcol1 * 128;
    int axor = arow & 15, b0x = bcol0 & 15, b1x = bcol1 & 15;
    // MFMA1: hidden
    f32x16 h0 = {}, h1 = {};
#pragma unroll
    for (int ks = 0; ks < 8; ++ks) {
        int chA = ks * 2 + g;
        short8 a8 = *(const short8*)(pa  + ((chA ^ axor) << 3));
        short8 b8 = *(const short8*)(pb0 + ((chA ^ b0x) << 3));
        short8 c8 = *(const short8*)(pb1 + ((chA ^ b1x) << 3));
        h0 = __builtin_amdgcn_mfma_f32_32x32x16_bf16(a8, b8, h0, 0, 0, 0);
        h1 = __builtin_amdgcn_mfma_f32_32x32x16_bf16(a8, c8, h1, 0, 0, 0);
    }
    // exp partial sums over valid rows (s < 50), per output col
    float p0 = 0.f, p1 = 0.f;
#pragma unroll
    for (int r = 0; r < 16; ++r) {
        int row = rt * 32 + (r & 3) + 8 * (r >> 2) + 4 * g;
        if (row < SS) { p0 += expf(h0[r]); p1 += expf(h1[r]); }
    }
    sred[bcol0 * 5 + rt * 2 + g] = p0;
    sred[bcol1 * 5 + rt * 2 + g] = p1;
    __syncthreads();
    // restage sb <- Wcomb_d (Wcat rows 512+d*128..+128); agg concurrently
#pragma unroll
    for (int q = 0; q < 8; ++q) {
        int x = t + q * 256;
        int r = x >> 4, ch = x & 15;
        short8 v = *(const short8*)(Wcat + (size_t)(512 + d * 128 + r) * 128 + ch * 8);
        *(short8*)(sb + r * 128 + ((ch ^ (r & 15)) << 3)) = v;
    }
    if (t < 128) {
        float s = sred[t * 5] + sred[t * 5 + 1] + sred[t * 5 + 2] + sred[t * 5 + 3];
        float a = logf(s);
        sagg[t] = a;
        aggw[b * 512 + d * 128 + t] = a;
    }
    __syncthreads();
    // MFMA2: kp
    f32x16 k0 = {}, k1 = {};
#pragma unroll
    for (int ks = 0; ks < 8; ++ks) {
        int chA = ks * 2 + g;
        short8 a8 = *(const short8*)(pa  + ((chA ^ axor) << 3));
        short8 b8 = *(const short8*)(pb0 + ((chA ^ b0x) << 3));
        short8 c8 = *(const short8*)(pb1 + ((chA ^ b1x) << 3));
        k0 = __builtin_amdgcn_mfma_f32_32x32x16_bf16(a8, b8, k0, 0, 0, 0);
        k1 = __builtin_amdgcn_mfma_f32_32x32x16_bf16(a8, c8, k1, 0, 0, 0);
    }
    // ap (reads sagg + global Ws; writes sap) — independent of MFMA2 operands
    if (t < 128) {
        const float* wr = Ws + t * 256;
        float acc = bsc[t];
        for (int ch = 0; ch < 32; ++ch) {
            float4 a4 = *(const float4*)(sagg + ch * 4);
            float4 w4 = *(const float4*)(wr + ch * 4);
            acc += a4.x * w4.x + a4.y * w4.y + a4.z * w4.z + a4.w * w4.w;
        }
        sap[t] = acc;
        apw[(b * DDk + d) * 128 + t] = acc;
    }
    __syncthreads();   // all waves done reading sa/sb; sap ready
    // scatter kp -> skp (swizzled f32, overlays sa + first half of sb)
#pragma unroll
    for (int r = 0; r < 16; ++r) {
        int row = rt * 32 + (r & 3) + 8 * (r >> 2) + 4 * g;
        int c0 = ct * 64 + lr, c1 = ct * 64 + 32 + lr;
        skp[row * 128 + ((((c0 >> 2) ^ (row & 7)) << 2) | (c0 & 3))] = k0[r];
        skp[row * 128 + ((((c1 >> 2) ^ (row & 7)) << 2) | (c1 & 3))] = k1[r];
    }
    __syncthreads();
    // score: thread (s = t>>2, oq = t&3) -> 32-o partial
    if (t < 200) {
        int s = t >> 2, oq = t & 3;
        float acc = 0.f;
#pragma unroll
        for (int c = 0; c < 8; ++c) {
            int ch = oq * 8 + c;
            float4 a4 = *(const float4*)(sap + ch * 4);
            float4 w4 = *(const float4*)(wsc + ch * 4);
            float4 k4 = *(const float4*)(&skp[s * 128 + ((ch ^ (s & 7)) << 2)]);
            acc += w4.x * fmaxf(a4.x + k4.x, 0.f) + w4.y * fmaxf(a4.y + k4.y, 0.f)
                 + w4.z * fmaxf(a4.z + k4.z, 0.f) + w4.w * fmaxf(a4.w + k4.w, 0.f);
        }
        spart[t] = acc;
    }
    __syncthreads();
    if (t < SS) {
        float v = spart[t * 4] + spart[t * 4 + 1] + spart[t * 4 + 2] + spart[t * 4 + 3];
        o_ds[b * (DDk * SS) + d * SS + t] = v;
    }
}

// ---------------------------------------------------------------------------
// k_cand: blocks 0..315: (64-i tile, d): MFMA cand GEMM -> LDS -> relu score.
//         block 316: demand_sim_loss from aggw.
// ---------------------------------------------------------------------------
__global__ __launch_bounds__(256) void k_cand(const unsigned short* __restrict__ Abf,
                                              const unsigned short* __restrict__ Wcat,
                                              const float* __restrict__ apw,
                                              const float* __restrict__ aggw,
                                              const float* __restrict__ wsc,
                                              float* __restrict__ o_dsc,
                                              float* __restrict__ o_loss) {
    __shared__ __align__(16) char lds[66048];
    int gid = blockIdx.x;
    int t = threadIdx.x;
    if (gid >= 316) {                       // ---- loss block ----
        float* nrm = (float*)lds;           // 128 floats
        if (t < 128) {
            const float* a = aggw + t * 128;
            float s = 0.f;
            for (int h = 0; h < 128; ++h) s += a[h] * a[h];
            nrm[t] = fmaxf(sqrtf(s), 1e-8f);
        }
        __syncthreads();
        float lb = 0.f;
        if (t < 32) {
            const float* a = aggw + t * 512;
            float i0 = 1.f / nrm[t * 4 + 0], i1 = 1.f / nrm[t * 4 + 1];
            float i2 = 1.f / nrm[t * 4 + 2], i3 = 1.f / nrm[t * 4 + 3];
            for (int h = 0; h < 128; ++h) {
                float u0 = a[h] * i0, u1 = a[128 + h] * i1;
                float u2 = a[256 + h] * i2, u3 = a[384 + h] * i3;
                float v = u0 + u1 + u2 + u3;
                lb += v * v - (u0 * u0 + u1 * u1 + u2 * u2 + u3 * u3);
            }
        }
        for (int off = 32; off; off >>= 1) lb += __shfl_down(lb, off);
        if (t == 0) o_loss[0] = lb / (float)(BB * DDk * (DDk - 1));
        return;
    }
    unsigned short* sa  = (unsigned short*)lds;              // 64x128 bf16
    unsigned short* sw  = (unsigned short*)(lds + 16384);    // 128x128 bf16
    float*          scp = (float*)lds;                       // 64x128 f32 (overlay)
    float*          sap = (float*)(lds + 49152);             // 32x128 f32
    float*          swv = (float*)(lds + 65536);             // 128 f32

    int tile = gid >> 2, d = gid & 3;
    int i0 = tile * 64;
    // stage sa: cand rows (zero-pad last tile)
#pragma unroll
    for (int q = 0; q < 4; ++q) {
        int x = t + q * 256;
        int r = x >> 4, ch = x & 15;
        short8 v = {0, 0, 0, 0, 0, 0, 0, 0};
        if (i0 + r < NI) v = *(const short8*)(Abf + (size_t)(NROWS_IN + i0 + r) * 128 + ch * 8);
        *(short8*)(sa + r * 128 + ((ch ^ (r & 15)) << 3)) = v;
    }
    // stage sw: Wcomb_d (Wcat rows 512+d*128 .. +128)
#pragma unroll
    for (int q = 0; q < 8; ++q) {
        int x = t + q * 256;
        int r = x >> 4, ch = x & 15;
        short8 v = *(const short8*)(Wcat + (size_t)(512 + d * 128 + r) * 128 + ch * 8);
        *(short8*)(sw + r * 128 + ((ch ^ (r & 15)) << 3)) = v;
    }
    // stage sap (ap rows for this d) + swv
    if (t < 128) swv[t] = wsc[t];
#pragma unroll
    for (int q = 0; q < 4; ++q) {
        int x = t + q * 256;                // 1024 float4s = 32x128 f32
        int b = x >> 5, ch = x & 31;
        float4 v = *(const float4*)(apw + (size_t)(b * 4 + d) * 128 + ch * 4);
        *(float4*)(sap + b * 128 + ((ch ^ (b & 7)) << 2)) = v;
    }
    __syncthreads();
    // GEMM: wave w: rows (w&1)*32, cols (w>>1)*64 (two 32x32 tiles)
    int w = t >> 6, lane = t & 63;
    int rbase = (w & 1) * 32, cbase = (w >> 1) * 64;
    int lr = lane & 31, g = lane >> 5;
    int arow = rbase + lr;
    int bcol0 = cbase + lr, bcol1 = cbase + 32 + lr;
    const unsigned short* pa  = sa + arow * 128;
    const unsigned short* pb0 = sw + bcol0 * 128;
    const unsigned short* pb1 = sw + bcol1 * 128;
    int axor = arow & 15, b0x = bcol0 & 15, b1x = bcol1 & 15;
    f32x16 acc0 = {}, acc1 = {};
#pragma unroll
    for (int ks = 0; ks < 8; ++ks) {
        int chA = ks * 2 + g;
        short8 a8 = *(const short8*)(pa  + ((chA ^ axor) << 3));
        short8 b8 = *(const short8*)(pb0 + ((chA ^ b0x) << 3));
        short8 c8 = *(const short8*)(pb1 + ((chA ^ b1x) << 3));
        acc0 = __builtin_amdgcn_mfma_f32_32x32x16_bf16(a8, b8, acc0, 0, 0, 0);
        acc1 = __builtin_amdgcn_mfma_f32_32x32x16_bf16(a8, c8, acc1, 0, 0, 0);
    }
    __syncthreads();                        // done reading sa/sw
    // scatter cp tile into scp (swizzled f32)
#pragma unroll
    for (int r = 0; r < 16; ++r) {
        int row = rbase + (r & 3) + 8 * (r >> 2) + 4 * g;
        int c0 = cbase + lr, c1 = cbase + 32 + lr;
        scp[row * 128 + ((((c0 >> 2) ^ (row & 7)) << 2) | (c0 & 3))] = acc0[r];
        scp[row * 128 + ((((c1 >> 2) ^ (row & 7)) << 2) | (c1 & 3))] = acc1[r];
    }
    __syncthreads();
    // score: thread (b = t>>3, gg = t&7) -> 8 i's
    int b = t >> 3, gg = t & 7;
    int bx = b & 7;
    float acc[8] = {0.f, 0.f, 0.f, 0.f, 0.f, 0.f, 0.f, 0.f};
    const float* arow2 = sap + b * 128;
    for (int ch = 0; ch < 32; ++ch) {
        float4 a4 = *(const float4*)(arow2 + ((ch ^ bx) << 2));
        float4 w4 = *(const float4*)(swv + ch * 4);
#pragma unroll
        for (int kk = 0; kk < 8; ++kk) {
            int il = kk * 8 + gg;
            float4 c4 = *(const float4*)(&scp[il * 128 + ((ch ^ (il & 7)) << 2)]);
            acc[kk] += w4.x * fmaxf(a4.x + c4.x, 0.f) + w4.y * fmaxf(a4.y + c4.y, 0.f)
                     + w4.z * fmaxf(a4.z + c4.z, 0.f) + w4.w * fmaxf(a4.w + c4.w, 0.f);
        }
    }
#pragma unroll
    for (int kk = 0; kk < 8; ++kk) {
        int i = i0 + kk * 8 + gg;
        if (i < NI) o_dsc[(size_t)b * (DDk * NI) + d * NI + i] = acc[kk];
    }
}

// ---------------------------------------------------------------------------
extern "C" void kernel_launch(void* const* d_in, const int* in_sizes, int n_in,
                              void* d_out, int out_size, void* d_ws, size_t ws_size,
                              hipStream_t stream) {
    const int*   inp  = (const int*)d_in[0];
    const int*   cand = (const int*)d_in[1];
    const float* et   = (const float*)d_in[2];
    const float* Wd   = (const float*)d_in[3];
    const float* Ws   = (const float*)d_in[4];
    const float* bsc  = (const float*)d_in[5];
    const float* wsc  = (const float*)d_in[6];

    float* out = (float*)d_out;
    float* o_ds   = out;                  // (B,D,S)    6400
    float* o_dsc  = out + 6400;           // (B,D,I)    640000
    float* o_emb  = out + 646400;         // (B,S,E)    204800
    float* o_cemb = out + 851200;         // (I,E)      640000
    float* o_loss = out + 1491200;        // scalar

    char* wsb = (char*)d_ws;
    unsigned short* Wcat = (unsigned short*)wsb;              // 1024x128 bf16
    unsigned short* Abf  = (unsigned short*)(wsb + 262144);   // 6600x128 bf16
    float* aggw = (float*)(wsb + 2097152);                    // 16384 f32
    float* apw  = aggw + 16384;                               // 16384 f32

    hipLaunchKernelGGL(k_prep, dim3(905), dim3(256), 0, stream,
                       inp, cand, et, Wd, Ws, Wcat, Abf, o_emb, o_cemb);
    hipLaunchKernelGGL(k_fused_mid, dim3(128), dim3(256), 0, stream,
                       Abf, Wcat, Ws, bsc, wsc, aggw, apw, o_ds);
    hipLaunchKernelGGL(k_cand, dim3(317), dim3(256), 0, stream,
                       Abf, Wcat, apw, aggw, wsc, o_dsc, o_loss);
}